// Round 8
// baseline (677.207 us; speedup 1.0000x reference)
//
#include <hip/hip_runtime.h>
#include <math.h>

#define DEV static __device__ __forceinline__

// DPP helpers — all cross-lane traffic is full-rate VALU DPP (no LDS pipe).
template<int CTRL>
DEV float qperm(float x) {
    return __int_as_float(__builtin_amdgcn_mov_dpp(__float_as_int(x), CTRL, 0xF, 0xF, true));
}
DEV float lx1f(float v) { return qperm<0xB1>(v); }   // xor lane bit0 (qubit2)
DEV float lx2f(float v) { return qperm<0x4E>(v); }   // xor lane bit1 (qubit3)
DEV float lx8f(float v) { return qperm<0x128>(v); }  // row_ror:8 = xor bit3 (qubit1)
// xor lane bit2 (qubit0): quad_perm[3,2,1,0] (i^3) then row_half_mirror (i^7) = i^4
DEV float lx4f(float v) { return qperm<0x141>(qperm<0x1B>(v)); }
DEV float rfl(float x)  { return __int_as_float(__builtin_amdgcn_readfirstlane(__float_as_int(x))); }

// Cheap sincos in REVOLUTIONS: v_fract + v_sin + v_cos.
DEV void fsincos(float rev, float* s, float* c) {
    float f = __builtin_amdgcn_fractf(rev);
    *s = __builtin_amdgcn_sinf(f);
    *c = __builtin_amdgcn_cosf(f);
}

// Rot on a lane-distributed qubit: a' = alpha*a + beta*p;
// alpha_r=Ur (SGPR), beta_i=Wi (SGPR), vA=z*u00i (VGPR), vB=z*u01r (VGPR).
DEV void rotd(float& ar, float& ai, float pr, float pi,
              float Ur, float Wi, float vA, float vB) {
    float nr = Ur*ar;
    nr = fmaf(-vA, ai, nr);
    nr = fmaf( vB, pr, nr);
    nr = fmaf(-Wi, pi, nr);
    float ni = Ur*ai;
    ni = fmaf( vA, ar, ni);
    ni = fmaf( vB, pi, ni);
    ni = fmaf( Wi, pr, ni);
    ar = nr; ai = ni;
}

__global__ __launch_bounds__(256, 4)
void qrnn_kernel(const float* __restrict__ inputs, const float* __restrict__ initial_t,
                 const float* __restrict__ p1, const float* __restrict__ p2,
                 const float* __restrict__ kbw, const float* __restrict__ ksw,
                 const float* __restrict__ w1, const float* __restrict__ cb1,
                 const float* __restrict__ w2, const float* __restrict__ cb2,
                 float* __restrict__ out, int B, int S)
{
    // 16 lanes per element; one complex amplitude per lane.
    // lane bit0->qubit2, bit1->qubit3, bit2->qubit0, bit3->qubit1.
    const int tid    = blockIdx.x * blockDim.x + threadIdx.x;
    const int lane16 = threadIdx.x & 15;
    const int e      = tid >> 4;
    if (e >= B) return;
    const bool B0 = (lane16 & 1) != 0;       // qubit2 bit
    const bool B1 = (lane16 & 2) != 0;       // qubit3 bit
    const bool B2 = (lane16 & 4) != 0;       // qubit0 bit
    const bool B3 = (lane16 & 8) != 0;       // qubit1 bit
    const int  j01 = lane16 & 3;             // dim / measurement class
    const float Z2 = B0 ? -1.f : 1.f;        // qubit2 Z-sign
    const float Z3 = B1 ? -1.f : 1.f;        // qubit3
    const float Z0 = B2 ? -1.f : 1.f;        // qubit0
    const float Z1 = B3 ? -1.f : 1.f;        // qubit1
    const float M01 = Z0*Z1, M12 = Z1*Z2, M23 = Z2*Z3;
    const float SGM = B1 ? Z0 : 1.f;         // fm_x fold of layer-2 CNOT(3,0)
    const float E3  = Z1;                    // measurement bit3 presign
    const float TA1 = (B0 == B1) ? -1.f : 1.f;          // chain A bit1 twist
    const float TA2 = (j01 == 0) ? 1.f : -1.f;          // chain A bit2 twist
    const bool  isC1 = (j01 == 1);
    // dest-sign correction * 1/256 (probs carry x256).
    // Presigned bit3 butterfly (w=Z1*p; r=w+swap(w)) yields UNIFORM T3 — no Z1
    // here (R7's Z1 factor was the bug). Classes 1-3 keep chain residual Z0.
    const float SCL = ((j01 == 0) ? 1.f : Z0) * (1.0f/256.0f);

    // Angles in REVOLUTIONS with -0.5 half-angle folded: stored = -rad/(4*pi).
    const float REVC = -0.07957747154594767f;   // -1/(4*pi)
    const float NQPI = -0.7853981633974483f;    // -pi/4

    // ---- one-time: 16 Rot matrices. Uniform parts -> SGPR, lane-signed -> VGPR.
    float Ur[4][4], Wi[4][4];   // [layer][qubit] SGPR
    float vA[4][4], vB[4][4];   // [layer][qubit] VGPR (zq folded)
    const float ZQ[4] = { Z0, Z1, Z2, Z3 };
    const float* PP[2] = { p1, p2 };
#pragma unroll
    for (int aI = 0; aI < 2; ++aI) {
        const float* pp = PP[aI];
#pragma unroll
        for (int l = 0; l < 2; ++l) {
            const int idx = aI*2 + l;
#pragma unroll
            for (int q = 0; q < 4; ++q) {
                float phi = pp[l*12 + q*3 + 0];
                float tht = pp[l*12 + q*3 + 1];
                float omg = pp[l*12 + q*3 + 2];
                float st, ct; sincosf(0.5f*tht, &st, &ct);
                float sA, cA, sB, cB;
                sincosf(0.5f*(phi + omg), &sA, &cA);
                sincosf(0.5f*(phi - omg), &sB, &cB);
                float u00r =  cA*ct, u00i = -sA*ct;
                float u01r = -cB*st, u01i = -sB*st;
                Ur[idx][q] = rfl(u00r);
                Wi[idx][q] = rfl(u01i);
                vA[idx][q] = ZQ[q] * u00i;
                vB[idx][q] = ZQ[q] * u01r;
            }
        }
    }

    // ---- KAN: lane mu_k computes h_k (Walsh-mask placement); others zero.
    // mu: h0->lane4, h1->lane8, h2->lane1, h3->lane2, h4->lane12, h5->lane9, h6->lane3.
    int kk = -1;
    if      (lane16 == 4)  kk = 0;
    else if (lane16 == 8)  kk = 1;
    else if (lane16 == 1)  kk = 2;
    else if (lane16 == 2)  kk = 3;
    else if (lane16 == 12) kk = 4;
    else if (lane16 == 9)  kk = 5;
    else if (lane16 == 3)  kk = 6;
    float Q1c[4], Q2c[4], Q3c[4], BWc[4], QS = 0.f;
#pragma unroll
    for (int j = 0; j < 4; ++j) {
        float q0c = 0.f, q1c = 0.f, q2c = 0.f, q3c = 0.f, bwc = 0.f;
        if (kk >= 0) {
            float sw0 = ksw[kk*16 + j*4 + 0], sw1 = ksw[kk*16 + j*4 + 1];
            float sw2 = ksw[kk*16 + j*4 + 2], sw3 = ksw[kk*16 + j*4 + 3];
            const float f = REVC / 48.0f;
            q0c = f * (sw0 + 23.f*sw1 + 23.f*sw2 + sw3);
            q1c = f * (-3.f*sw0 - 15.f*sw1 + 15.f*sw2 + 3.f*sw3);
            q2c = f * (3.f*sw0 - 3.f*sw1 - 3.f*sw2 + 3.f*sw3);
            q3c = f * (-sw0 + 3.f*sw1 - 3.f*sw2 + sw3);
            bwc = REVC * kbw[kk*4 + j];
        }
        Q1c[j] = q1c; Q2c[j] = q2c; Q3c[j] = q3c; BWc[j] = bwc; QS += q0c;
    }

    // ---- initial SIG (per-lane feature-map phase, revolutions)
    float SIG;
    {
        const float* it = initial_t + (long)e*7;
        float h0 = REVC*it[0], h1 = REVC*it[1], h2 = REVC*it[2], h3 = REVC*it[3];
        float h4 = REVC*it[4], h5 = REVC*it[5], h6 = REVC*it[6];
        SIG = Z0*h0;
        SIG = fmaf(Z1, h1, SIG);
        SIG = fmaf(Z2, h2, SIG);
        SIG = fmaf(Z3, h3, SIG);
        SIG = fmaf(M01, h4, SIG);
        SIG = fmaf(M12, h5, SIG);
        SIG = fmaf(M23, h6, SIG);
    }

    const float4* inp4 = (const float4*)inputs;
    const long basei = (long)e * S;
    float4 xc = inp4[basei];
    float xk = 0.f;

#pragma unroll 1
    for (int t = 0; t < S; ++t) {
        const int tn = (t + 1 < S) ? t + 1 : S - 1;
        float4 xn = inp4[basei + tn];

        // ---- fm(hidden) on |0000>: amp = e^{i*2pi*SIG}
        float ar, ai;
        fsincos(SIG, &ai, &ar);

        // ---- ansatz(p1), fm(x), ansatz(p2).
        // Layer-2 CNOT(3,0) folded into fm_x (SGM); layer-4 ring folded into
        // the measurement Walsh masks.
#pragma unroll
        for (int l = 0; l < 4; ++l) {
            // Rot q0 (bit2), q1 (bit3), q2 (bit0), q3 (bit1)
            { float pr = lx4f(ar), pi = lx4f(ai);
              rotd(ar, ai, pr, pi, Ur[l][0], Wi[l][0], vA[l][0], vB[l][0]); }
            { float pr = lx8f(ar), pi = lx8f(ai);
              rotd(ar, ai, pr, pi, Ur[l][1], Wi[l][1], vA[l][1], vB[l][1]); }
            { float pr = lx1f(ar), pi = lx1f(ai);
              rotd(ar, ai, pr, pi, Ur[l][2], Wi[l][2], vA[l][2], vB[l][2]); }
            { float pr = lx2f(ar), pi = lx2f(ai);
              rotd(ar, ai, pr, pi, Ur[l][3], Wi[l][3], vA[l][3], vB[l][3]); }
            if (l < 3) {
                // CNOT(0,1): control qubit0(bit2), target qubit1(bit3)
                { float vr = lx8f(ar), vi = lx8f(ai);
                  ar = B2 ? vr : ar; ai = B2 ? vi : ai; }
                // merged CNOT(1,2)+CNOT(2,3): select on control qubit1(bit3)
                { float c6r = qperm<0x6C>(ar), c3r = qperm<0x39>(ar);
                  float c6i = qperm<0x6C>(ai), c3i = qperm<0x39>(ai);
                  ar = B3 ? c3r : c6r; ai = B3 ? c3i : c6i; }
                if (l != 1) {
                    // CNOT(3,0): control qubit3(bit1), target qubit0(bit2)
                    float vr = lx4f(ar), vi = lx4f(ai);
                    ar = B1 ? vr : ar; ai = B1 ? vi : ai;
                }
            }
            if (l == 1) {
                // ---- fm(x_embed): H^{x4} (unscaled) + diag phase
                float hx0 = REVC*xc.x, hx1 = REVC*xc.y, hx2 = REVC*xc.z, hx3 = REVC*xc.w;
                float u0 = fmaf(4.f, hx0, 1.f);
                float u1 = fmaf(4.f, hx1, 1.f);
                float u2 = fmaf(4.f, hx2, 1.f);
                float u3 = fmaf(4.f, hx3, 1.f);
                float he4 = NQPI * (u0*u1);
                float he5 = NQPI * (u1*u2);
                float he6 = NQPI * (u2*u3);
                // H q0 (bit2) + folded CNOT(3,0) sign SGM
                { float pr = lx4f(ar), pi = lx4f(ai);
                  ar = fmaf(Z0, ar, pr) * SGM;
                  ai = fmaf(Z0, ai, pi) * SGM; }
                // H q1 (bit3)
                { float pr = lx8f(ar), pi = lx8f(ai);
                  ar = fmaf(Z1, ar, pr); ai = fmaf(Z1, ai, pi); }
                // H q2 (bit0)
                { float pr = lx1f(ar), pi = lx1f(ai);
                  ar = fmaf(Z2, ar, pr); ai = fmaf(Z2, ai, pi); }
                // H q3 (bit1)
                { float pr = lx2f(ar), pi = lx2f(ai);
                  ar = fmaf(Z3, ar, pr); ai = fmaf(Z3, ai, pi); }
                // diag phase
                float sigx = Z0*hx0;
                sigx = fmaf(Z1, hx1, sigx);
                sigx = fmaf(Z2, hx2, sigx);
                sigx = fmaf(Z3, hx3, sigx);
                sigx = fmaf(M01, he4, sigx);
                sigx = fmaf(M12, he5, sigx);
                sigx = fmaf(M23, he6, sigx);
                float s, c;
                fsincos(sigx, &s, &c);
                float nr = ar*c - ai*s;
                float ni = ai*c + ar*s;
                ar = nr; ai = ni;
            }
        }

        // ---- measurement: layer-4 ring folded -> Walsh masks (lane bits):
        // ev0:{b0,b1,b3} ev1:{b2,b3} ev2:{b0,b2,b3} ev3:{b0,b1,b2,b3}
        {
            float p = fmaf(ai, ai, ar*ar);      // prob x256
            float w = E3 * p;                   // bit3 presign
            float r = w + lx8f(w);              // bit3-signed reduce, UNIFORM T3
            float m1 = lx1f(r);
            float rA = r - m1;                  // chain A bit0 (twist -1)
            float rB = r + m1;                  // chain B bit0 (twist +1)
            rA = fmaf(TA1, lx2f(rA), rA);       // chain A bit1
            rB = rB + lx2f(rB);                 // chain B bit1 (+1)
            rA = fmaf(TA2, lx4f(rA), rA);       // chain A bit2
            rB = rB - lx4f(rB);                 // chain B bit2 (-1, dest Z0)
            float pre = isC1 ? rB : rA;         // class j holds ev_j (pre-sign)
            xk = pre * SCL;
        }

        // ---- KAN: silu per dim-lane, quad broadcast, h at mu-lanes, WHT->SIG
        {
            float xq0 = qperm<0x00>(xk), xq1 = qperm<0x55>(xk);
            float xq2 = qperm<0xAA>(xk), xq3 = qperm<0xFF>(xk);
            float eneg = __builtin_amdgcn_exp2f(xk * -1.44269504088896f);
            float sl = xk * __builtin_amdgcn_rcpf(1.0f + eneg);
            float sq0 = qperm<0x00>(sl), sq1 = qperm<0x55>(sl);
            float sq2 = qperm<0xAA>(sl), sq3 = qperm<0xFF>(sl);
            float h = QS;
            { float tpoly = fmaf(Q3c[0], xq0, Q2c[0]);
              tpoly = fmaf(tpoly, xq0, Q1c[0]);
              h = fmaf(tpoly, xq0, h);
              h = fmaf(BWc[0], sq0, h); }
            { float tpoly = fmaf(Q3c[1], xq1, Q2c[1]);
              tpoly = fmaf(tpoly, xq1, Q1c[1]);
              h = fmaf(tpoly, xq1, h);
              h = fmaf(BWc[1], sq1, h); }
            { float tpoly = fmaf(Q3c[2], xq2, Q2c[2]);
              tpoly = fmaf(tpoly, xq2, Q1c[2]);
              h = fmaf(tpoly, xq2, h);
              h = fmaf(BWc[2], sq2, h); }
            { float tpoly = fmaf(Q3c[3], xq3, Q2c[3]);
              tpoly = fmaf(tpoly, xq3, Q1c[3]);
              h = fmaf(tpoly, xq3, h);
              h = fmaf(BWc[3], sq3, h); }
            // 4-round WHT (own-twist form): SIG(d) = sum_k h_k (-1)^{<d,mu_k>}
            h = fmaf(Z2, h, lx1f(h));   // bit0
            h = fmaf(Z3, h, lx2f(h));   // bit1
            h = fmaf(Z0, h, lx4f(h));   // bit2
            SIG = fmaf(Z1, h, lx8f(h)); // bit3
        }

        xc = xn;
    }

    // ---- classifier head: broadcast ev0..3, lane 0 writes
    {
        float xq0 = qperm<0x00>(xk), xq1 = qperm<0x55>(xk);
        float xq2 = qperm<0xAA>(xk), xq3 = qperm<0xFF>(xk);
        if (lane16 == 0) {
            float acc = cb2[0];
#pragma unroll
            for (int i = 0; i < 16; ++i) {
                float h = cb1[i] + w1[i*4+0]*xq0 + w1[i*4+1]*xq1
                        + w1[i*4+2]*xq2 + w1[i*4+3]*xq3;
                h = fmaxf(h, 0.0f);
                acc += w2[i]*h;
            }
            out[e] = acc;
        }
    }
}

extern "C" void kernel_launch(void* const* d_in, const int* in_sizes, int n_in,
                              void* d_out, int out_size, void* d_ws, size_t ws_size,
                              hipStream_t stream) {
    const float* inputs    = (const float*)d_in[0];
    const float* initial_t = (const float*)d_in[1];
    const float* p1        = (const float*)d_in[2];
    const float* p2        = (const float*)d_in[3];
    const float* kbw       = (const float*)d_in[4];
    const float* ksw       = (const float*)d_in[5];
    const float* w1        = (const float*)d_in[6];
    const float* cb1       = (const float*)d_in[7];
    const float* w2        = (const float*)d_in[8];
    const float* cb2       = (const float*)d_in[9];

    const int B = in_sizes[1] / 7;            // 16384
    const int S = in_sizes[0] / (B * 4);      // 256

    const int threads = B * 16;               // 16 lanes per element
    const int block = 256;
    const int grid = (threads + block - 1) / block;   // 1024 blocks -> 4 waves/SIMD

    qrnn_kernel<<<grid, block, 0, stream>>>(inputs, initial_t, p1, p2, kbw, ksw,
                                            w1, cb1, w2, cb2, (float*)d_out, B, S);
}

// Round 9
// 675.683 us; speedup vs baseline: 1.0023x; 1.0023x over previous
//
#include <hip/hip_runtime.h>
#include <math.h>

#define DEV static __device__ __forceinline__

// DPP helpers — all cross-lane traffic is full-rate VALU DPP (no LDS pipe).
template<int CTRL>
DEV float qperm(float x) {
    return __int_as_float(__builtin_amdgcn_mov_dpp(__float_as_int(x), CTRL, 0xF, 0xF, true));
}
DEV float lx1f(float v) { return qperm<0xB1>(v); }   // xor lane bit0 (qubit2)
DEV float lx2f(float v) { return qperm<0x4E>(v); }   // xor lane bit1 (qubit3)
DEV float lx8f(float v) { return qperm<0x128>(v); }  // row_ror:8 = xor bit3 (qubit1)
// xor lane bit2 (qubit0): quad_perm[3,2,1,0] (i^3) then row_half_mirror (i^7) = i^4
DEV float lx4f(float v) { return qperm<0x141>(qperm<0x1B>(v)); }
DEV float rfl(float x)  { return __int_as_float(__builtin_amdgcn_readfirstlane(__float_as_int(x))); }

// Cheap sincos in REVOLUTIONS: v_fract + v_sin + v_cos.
DEV void fsincos(float rev, float* s, float* c) {
    float f = __builtin_amdgcn_fractf(rev);
    *s = __builtin_amdgcn_sinf(f);
    *c = __builtin_amdgcn_cosf(f);
}

// Rot on a lane-distributed qubit: a' = alpha*a + beta*p;
// alpha_r=Ur (SGPR), beta_i=Wi (SGPR), vA=z*u00i (VGPR), vB=z*u01r (VGPR).
DEV void rotd(float& ar, float& ai, float pr, float pi,
              float Ur, float Wi, float vA, float vB) {
    float nr = Ur*ar;
    nr = fmaf(-vA, ai, nr);
    nr = fmaf( vB, pr, nr);
    nr = fmaf(-Wi, pi, nr);
    float ni = Ur*ai;
    ni = fmaf( vA, ar, ni);
    ni = fmaf( vB, pi, ni);
    ni = fmaf( Wi, pr, ni);
    ar = nr; ai = ni;
}

__global__ __launch_bounds__(256)
__attribute__((amdgpu_waves_per_eu(4, 4)))   // pin: VGPR budget 128, no spill-to-64
void qrnn_kernel(const float* __restrict__ inputs, const float* __restrict__ initial_t,
                 const float* __restrict__ p1, const float* __restrict__ p2,
                 const float* __restrict__ kbw, const float* __restrict__ ksw,
                 const float* __restrict__ w1, const float* __restrict__ cb1,
                 const float* __restrict__ w2, const float* __restrict__ cb2,
                 float* __restrict__ out, int B, int S)
{
    // 16 lanes per element; one complex amplitude per lane.
    // lane bit0->qubit2, bit1->qubit3, bit2->qubit0, bit3->qubit1.
    const int tid    = blockIdx.x * blockDim.x + threadIdx.x;
    const int lane16 = threadIdx.x & 15;
    const int e      = tid >> 4;
    if (e >= B) return;
    const bool B0 = (lane16 & 1) != 0;       // qubit2 bit
    const bool B1 = (lane16 & 2) != 0;       // qubit3 bit
    const bool B2 = (lane16 & 4) != 0;       // qubit0 bit
    const bool B3 = (lane16 & 8) != 0;       // qubit1 bit
    const int  j01 = lane16 & 3;             // dim / measurement class
    const float Z2 = B0 ? -1.f : 1.f;        // qubit2 Z-sign
    const float Z3 = B1 ? -1.f : 1.f;        // qubit3
    const float Z0 = B2 ? -1.f : 1.f;        // qubit0
    const float Z1 = B3 ? -1.f : 1.f;        // qubit1
    const float M01 = Z0*Z1, M12 = Z1*Z2, M23 = Z2*Z3;
    const float SGM = B1 ? Z0 : 1.f;         // fm_x fold of layer-2 CNOT(3,0)
    const float E3  = Z1;                    // measurement bit3 presign
    const float TA1 = (B0 == B1) ? -1.f : 1.f;          // chain A bit1 twist
    const float TA2 = (j01 == 0) ? 1.f : -1.f;          // chain A bit2 twist
    const bool  isC1 = (j01 == 1);
    // dest-sign correction * 1/256 (probs carry x256). Presigned bit3
    // butterfly yields UNIFORM T3; classes 1-3 keep chain residual Z0.
    const float SCL = ((j01 == 0) ? 1.f : Z0) * (1.0f/256.0f);

    // Angles in REVOLUTIONS with -0.5 half-angle folded: stored = -rad/(4*pi).
    const float REVC = -0.07957747154594767f;   // -1/(4*pi)
    const float NQPI = -0.7853981633974483f;    // -pi/4

    // ---- one-time: 16 Rot matrices. Uniform parts -> SGPR, lane-signed -> VGPR.
    float Ur[4][4], Wi[4][4];   // [layer][qubit] SGPR
    float vA[4][4], vB[4][4];   // [layer][qubit] VGPR (zq folded)
    const float ZQ[4] = { Z0, Z1, Z2, Z3 };
    const float* PP[2] = { p1, p2 };
#pragma unroll
    for (int aI = 0; aI < 2; ++aI) {
        const float* pp = PP[aI];
#pragma unroll
        for (int l = 0; l < 2; ++l) {
            const int idx = aI*2 + l;
#pragma unroll
            for (int q = 0; q < 4; ++q) {
                float phi = pp[l*12 + q*3 + 0];
                float tht = pp[l*12 + q*3 + 1];
                float omg = pp[l*12 + q*3 + 2];
                float st, ct; sincosf(0.5f*tht, &st, &ct);
                float sA, cA, sB, cB;
                sincosf(0.5f*(phi + omg), &sA, &cA);
                sincosf(0.5f*(phi - omg), &sB, &cB);
                float u00r =  cA*ct, u00i = -sA*ct;
                float u01r = -cB*st, u01i = -sB*st;
                Ur[idx][q] = rfl(u00r);
                Wi[idx][q] = rfl(u01i);
                vA[idx][q] = ZQ[q] * u00i;
                vB[idx][q] = ZQ[q] * u01r;
            }
        }
    }

    // ---- KAN: lane mu_k computes h_k (Walsh-mask placement); others zero.
    // mu: h0->lane4, h1->lane8, h2->lane1, h3->lane2, h4->lane12, h5->lane9, h6->lane3.
    int kk = -1;
    if      (lane16 == 4)  kk = 0;
    else if (lane16 == 8)  kk = 1;
    else if (lane16 == 1)  kk = 2;
    else if (lane16 == 2)  kk = 3;
    else if (lane16 == 12) kk = 4;
    else if (lane16 == 9)  kk = 5;
    else if (lane16 == 3)  kk = 6;
    float Q1c[4], Q2c[4], Q3c[4], BWc[4], QS = 0.f;
#pragma unroll
    for (int j = 0; j < 4; ++j) {
        float q0c = 0.f, q1c = 0.f, q2c = 0.f, q3c = 0.f, bwc = 0.f;
        if (kk >= 0) {
            float sw0 = ksw[kk*16 + j*4 + 0], sw1 = ksw[kk*16 + j*4 + 1];
            float sw2 = ksw[kk*16 + j*4 + 2], sw3 = ksw[kk*16 + j*4 + 3];
            const float f = REVC / 48.0f;
            q0c = f * (sw0 + 23.f*sw1 + 23.f*sw2 + sw3);
            q1c = f * (-3.f*sw0 - 15.f*sw1 + 15.f*sw2 + 3.f*sw3);
            q2c = f * (3.f*sw0 - 3.f*sw1 - 3.f*sw2 + 3.f*sw3);
            q3c = f * (-sw0 + 3.f*sw1 - 3.f*sw2 + sw3);
            bwc = REVC * kbw[kk*4 + j];
        }
        Q1c[j] = q1c; Q2c[j] = q2c; Q3c[j] = q3c; BWc[j] = bwc; QS += q0c;
    }

    // ---- initial SIG (per-lane feature-map phase, revolutions)
    float SIG;
    {
        const float* it = initial_t + (long)e*7;
        float h0 = REVC*it[0], h1 = REVC*it[1], h2 = REVC*it[2], h3 = REVC*it[3];
        float h4 = REVC*it[4], h5 = REVC*it[5], h6 = REVC*it[6];
        SIG = Z0*h0;
        SIG = fmaf(Z1, h1, SIG);
        SIG = fmaf(Z2, h2, SIG);
        SIG = fmaf(Z3, h3, SIG);
        SIG = fmaf(M01, h4, SIG);
        SIG = fmaf(M12, h5, SIG);
        SIG = fmaf(M23, h6, SIG);
    }

    const float4* inp4 = (const float4*)inputs;
    const long basei = (long)e * S;
    float4 xc = inp4[basei];
    float xk = 0.f;

#pragma unroll 1
    for (int t = 0; t < S; ++t) {
        const int tn = (t + 1 < S) ? t + 1 : S - 1;
        float4 xn = inp4[basei + tn];

        // ---- fm(hidden) on |0000>: amp = e^{i*2pi*SIG}
        float ar, ai;
        fsincos(SIG, &ai, &ar);

        // ---- ansatz(p1), fm(x), ansatz(p2).
        // Layer-2 CNOT(3,0) folded into fm_x (SGM); layer-4 ring folded into
        // the measurement Walsh masks.
#pragma unroll
        for (int l = 0; l < 4; ++l) {
            // Rot q0 (bit2), q1 (bit3), q2 (bit0), q3 (bit1)
            { float pr = lx4f(ar), pi = lx4f(ai);
              rotd(ar, ai, pr, pi, Ur[l][0], Wi[l][0], vA[l][0], vB[l][0]); }
            { float pr = lx8f(ar), pi = lx8f(ai);
              rotd(ar, ai, pr, pi, Ur[l][1], Wi[l][1], vA[l][1], vB[l][1]); }
            { float pr = lx1f(ar), pi = lx1f(ai);
              rotd(ar, ai, pr, pi, Ur[l][2], Wi[l][2], vA[l][2], vB[l][2]); }
            { float pr = lx2f(ar), pi = lx2f(ai);
              rotd(ar, ai, pr, pi, Ur[l][3], Wi[l][3], vA[l][3], vB[l][3]); }
            if (l < 3) {
                // CNOT(0,1): control qubit0(bit2), target qubit1(bit3)
                { float vr = lx8f(ar), vi = lx8f(ai);
                  ar = B2 ? vr : ar; ai = B2 ? vi : ai; }
                // merged CNOT(1,2)+CNOT(2,3): select on control qubit1(bit3)
                { float c6r = qperm<0x6C>(ar), c3r = qperm<0x39>(ar);
                  float c6i = qperm<0x6C>(ai), c3i = qperm<0x39>(ai);
                  ar = B3 ? c3r : c6r; ai = B3 ? c3i : c6i; }
                if (l != 1) {
                    // CNOT(3,0): control qubit3(bit1), target qubit0(bit2)
                    float vr = lx4f(ar), vi = lx4f(ai);
                    ar = B1 ? vr : ar; ai = B1 ? vi : ai;
                }
            }
            if (l == 1) {
                // ---- fm(x_embed): H^{x4} (unscaled) + diag phase
                float hx0 = REVC*xc.x, hx1 = REVC*xc.y, hx2 = REVC*xc.z, hx3 = REVC*xc.w;
                float u0 = fmaf(4.f, hx0, 1.f);
                float u1 = fmaf(4.f, hx1, 1.f);
                float u2 = fmaf(4.f, hx2, 1.f);
                float u3 = fmaf(4.f, hx3, 1.f);
                float he4 = NQPI * (u0*u1);
                float he5 = NQPI * (u1*u2);
                float he6 = NQPI * (u2*u3);
                // H q0 (bit2) + folded CNOT(3,0) sign SGM
                { float pr = lx4f(ar), pi = lx4f(ai);
                  ar = fmaf(Z0, ar, pr) * SGM;
                  ai = fmaf(Z0, ai, pi) * SGM; }
                // H q1 (bit3)
                { float pr = lx8f(ar), pi = lx8f(ai);
                  ar = fmaf(Z1, ar, pr); ai = fmaf(Z1, ai, pi); }
                // H q2 (bit0)
                { float pr = lx1f(ar), pi = lx1f(ai);
                  ar = fmaf(Z2, ar, pr); ai = fmaf(Z2, ai, pi); }
                // H q3 (bit1)
                { float pr = lx2f(ar), pi = lx2f(ai);
                  ar = fmaf(Z3, ar, pr); ai = fmaf(Z3, ai, pi); }
                // diag phase
                float sigx = Z0*hx0;
                sigx = fmaf(Z1, hx1, sigx);
                sigx = fmaf(Z2, hx2, sigx);
                sigx = fmaf(Z3, hx3, sigx);
                sigx = fmaf(M01, he4, sigx);
                sigx = fmaf(M12, he5, sigx);
                sigx = fmaf(M23, he6, sigx);
                float s, c;
                fsincos(sigx, &s, &c);
                float nr = ar*c - ai*s;
                float ni = ai*c + ar*s;
                ar = nr; ai = ni;
            }
        }

        // ---- measurement: layer-4 ring folded -> Walsh masks (lane bits):
        // ev0:{b0,b1,b3} ev1:{b2,b3} ev2:{b0,b2,b3} ev3:{b0,b1,b2,b3}
        {
            float p = fmaf(ai, ai, ar*ar);      // prob x256
            float w = E3 * p;                   // bit3 presign
            float r = w + lx8f(w);              // bit3-signed reduce, UNIFORM T3
            float m1 = lx1f(r);
            float rA = r - m1;                  // chain A bit0 (twist -1)
            float rB = r + m1;                  // chain B bit0 (twist +1)
            rA = fmaf(TA1, lx2f(rA), rA);       // chain A bit1
            rB = rB + lx2f(rB);                 // chain B bit1 (+1)
            rA = fmaf(TA2, lx4f(rA), rA);       // chain A bit2
            rB = rB - lx4f(rB);                 // chain B bit2 (-1, dest Z0)
            float pre = isC1 ? rB : rA;         // class j holds ev_j (pre-sign)
            xk = pre * SCL;
        }

        // ---- KAN: silu per dim-lane, quad broadcast, h at mu-lanes, WHT->SIG
        {
            float xq0 = qperm<0x00>(xk), xq1 = qperm<0x55>(xk);
            float xq2 = qperm<0xAA>(xk), xq3 = qperm<0xFF>(xk);
            float eneg = __builtin_amdgcn_exp2f(xk * -1.44269504088896f);
            float sl = xk * __builtin_amdgcn_rcpf(1.0f + eneg);
            float sq0 = qperm<0x00>(sl), sq1 = qperm<0x55>(sl);
            float sq2 = qperm<0xAA>(sl), sq3 = qperm<0xFF>(sl);
            float h = QS;
            { float tpoly = fmaf(Q3c[0], xq0, Q2c[0]);
              tpoly = fmaf(tpoly, xq0, Q1c[0]);
              h = fmaf(tpoly, xq0, h);
              h = fmaf(BWc[0], sq0, h); }
            { float tpoly = fmaf(Q3c[1], xq1, Q2c[1]);
              tpoly = fmaf(tpoly, xq1, Q1c[1]);
              h = fmaf(tpoly, xq1, h);
              h = fmaf(BWc[1], sq1, h); }
            { float tpoly = fmaf(Q3c[2], xq2, Q2c[2]);
              tpoly = fmaf(tpoly, xq2, Q1c[2]);
              h = fmaf(tpoly, xq2, h);
              h = fmaf(BWc[2], sq2, h); }
            { float tpoly = fmaf(Q3c[3], xq3, Q2c[3]);
              tpoly = fmaf(tpoly, xq3, Q1c[3]);
              h = fmaf(tpoly, xq3, h);
              h = fmaf(BWc[3], sq3, h); }
            // 4-round WHT (own-twist form): SIG(d) = sum_k h_k (-1)^{<d,mu_k>}
            h = fmaf(Z2, h, lx1f(h));   // bit0
            h = fmaf(Z3, h, lx2f(h));   // bit1
            h = fmaf(Z0, h, lx4f(h));   // bit2
            SIG = fmaf(Z1, h, lx8f(h)); // bit3
        }

        xc = xn;
    }

    // ---- classifier head: broadcast ev0..3, lane 0 writes
    {
        float xq0 = qperm<0x00>(xk), xq1 = qperm<0x55>(xk);
        float xq2 = qperm<0xAA>(xk), xq3 = qperm<0xFF>(xk);
        if (lane16 == 0) {
            float acc = cb2[0];
#pragma unroll
            for (int i = 0; i < 16; ++i) {
                float h = cb1[i] + w1[i*4+0]*xq0 + w1[i*4+1]*xq1
                        + w1[i*4+2]*xq2 + w1[i*4+3]*xq3;
                h = fmaxf(h, 0.0f);
                acc += w2[i]*h;
            }
            out[e] = acc;
        }
    }
}

extern "C" void kernel_launch(void* const* d_in, const int* in_sizes, int n_in,
                              void* d_out, int out_size, void* d_ws, size_t ws_size,
                              hipStream_t stream) {
    const float* inputs    = (const float*)d_in[0];
    const float* initial_t = (const float*)d_in[1];
    const float* p1        = (const float*)d_in[2];
    const float* p2        = (const float*)d_in[3];
    const float* kbw       = (const float*)d_in[4];
    const float* ksw       = (const float*)d_in[5];
    const float* w1        = (const float*)d_in[6];
    const float* cb1       = (const float*)d_in[7];
    const float* w2        = (const float*)d_in[8];
    const float* cb2       = (const float*)d_in[9];

    const int B = in_sizes[1] / 7;            // 16384
    const int S = in_sizes[0] / (B * 4);      // 256

    const int threads = B * 16;               // 16 lanes per element
    const int block = 256;
    const int grid = (threads + block - 1) / block;   // 1024 blocks -> 4 waves/SIMD

    qrnn_kernel<<<grid, block, 0, stream>>>(inputs, initial_t, p1, p2, kbw, ksw,
                                            w1, cb1, w2, cb2, (float*)d_out, B, S);
}

// Round 10
// 666.222 us; speedup vs baseline: 1.0165x; 1.0142x over previous
//
#include <hip/hip_runtime.h>
#include <math.h>

#define DEV static __device__ __forceinline__

// DPP helpers — all cross-lane traffic is full-rate VALU DPP (no LDS pipe).
template<int CTRL>
DEV float qperm(float x) {
    return __int_as_float(__builtin_amdgcn_mov_dpp(__float_as_int(x), CTRL, 0xF, 0xF, true));
}
DEV float lx1f(float v) { return qperm<0xB1>(v); }   // xor lane bit0 (qubit2)
DEV float lx2f(float v) { return qperm<0x4E>(v); }   // xor lane bit1 (qubit3)
DEV float lx8f(float v) { return qperm<0x128>(v); }  // row_ror:8 = xor bit3 (qubit1)
// xor lane bit2 (qubit0): quad_perm[3,2,1,0] (i^3) then row_half_mirror (i^7) = i^4
DEV float lx4f(float v) { return qperm<0x141>(qperm<0x1B>(v)); }
DEV float rfl(float x)  { return __int_as_float(__builtin_amdgcn_readfirstlane(__float_as_int(x))); }

// Cheap sincos in REVOLUTIONS: v_fract + v_sin + v_cos.
DEV void fsincos(float rev, float* s, float* c) {
    float f = __builtin_amdgcn_fractf(rev);
    *s = __builtin_amdgcn_sinf(f);
    *c = __builtin_amdgcn_cosf(f);
}

// Rot on a lane-distributed qubit: a' = alpha*a + beta*p;
// alpha_r=Ur (SGPR), beta_i=Wi (SGPR), vA=z*u00i (VGPR), vB=z*u01r (VGPR).
DEV void rotd(float& ar, float& ai, float pr, float pi,
              float Ur, float Wi, float vA, float vB) {
    float nr = Ur*ar;
    nr = fmaf(-vA, ai, nr);
    nr = fmaf( vB, pr, nr);
    nr = fmaf(-Wi, pi, nr);
    float ni = Ur*ai;
    ni = fmaf( vA, ar, ni);
    ni = fmaf( vB, pi, ni);
    ni = fmaf( Wi, pr, ni);
    ar = nr; ai = ni;
}

// launch_bounds(256, 2): min 2 waves/EU -> VGPR cap 256; allocator takes its
// natural ~80-100 with NO spill (R5/R6 evidence). R8/R9's (256,4) made it
// squeeze to 64 VGPR + 53 MB scratch spill for occupancy the grid can't use.
__global__ __launch_bounds__(256, 2)
void qrnn_kernel(const float* __restrict__ inputs, const float* __restrict__ initial_t,
                 const float* __restrict__ p1, const float* __restrict__ p2,
                 const float* __restrict__ kbw, const float* __restrict__ ksw,
                 const float* __restrict__ w1, const float* __restrict__ cb1,
                 const float* __restrict__ w2, const float* __restrict__ cb2,
                 float* __restrict__ out, int B, int S)
{
    // 16 lanes per element; one complex amplitude per lane.
    // lane bit0->qubit2, bit1->qubit3, bit2->qubit0, bit3->qubit1.
    const int tid    = blockIdx.x * blockDim.x + threadIdx.x;
    const int lane16 = threadIdx.x & 15;
    const int e      = tid >> 4;
    if (e >= B) return;
    const bool B0 = (lane16 & 1) != 0;       // qubit2 bit
    const bool B1 = (lane16 & 2) != 0;       // qubit3 bit
    const bool B2 = (lane16 & 4) != 0;       // qubit0 bit
    const bool B3 = (lane16 & 8) != 0;       // qubit1 bit
    const int  j01 = lane16 & 3;             // dim / measurement class
    const float Z2 = B0 ? -1.f : 1.f;        // qubit2 Z-sign
    const float Z3 = B1 ? -1.f : 1.f;        // qubit3
    const float Z0 = B2 ? -1.f : 1.f;        // qubit0
    const float Z1 = B3 ? -1.f : 1.f;        // qubit1
    const float M01 = Z0*Z1, M12 = Z1*Z2, M23 = Z2*Z3;
    const float SGM = B1 ? Z0 : 1.f;         // fm_x fold of layer-2 CNOT(3,0)
    const float E3  = Z1;                    // measurement bit3 presign
    const float TA1 = (B0 == B1) ? -1.f : 1.f;          // chain A bit1 twist
    const float TA2 = (j01 == 0) ? 1.f : -1.f;          // chain A bit2 twist
    const bool  isC1 = (j01 == 1);
    // dest-sign correction * 1/256 (probs carry x256). Presigned bit3
    // butterfly yields UNIFORM T3; classes 1-3 keep chain residual Z0.
    const float SCL = ((j01 == 0) ? 1.f : Z0) * (1.0f/256.0f);

    // Angles in REVOLUTIONS with -0.5 half-angle folded: stored = -rad/(4*pi).
    const float REVC = -0.07957747154594767f;   // -1/(4*pi)
    const float NQPI = -0.7853981633974483f;    // -pi/4

    // ---- one-time: 16 Rot matrices. Uniform parts -> SGPR, lane-signed -> VGPR.
    float Ur[4][4], Wi[4][4];   // [layer][qubit] SGPR
    float vA[4][4], vB[4][4];   // [layer][qubit] VGPR (zq folded)
    const float ZQ[4] = { Z0, Z1, Z2, Z3 };
    const float* PP[2] = { p1, p2 };
#pragma unroll
    for (int aI = 0; aI < 2; ++aI) {
        const float* pp = PP[aI];
#pragma unroll
        for (int l = 0; l < 2; ++l) {
            const int idx = aI*2 + l;
#pragma unroll
            for (int q = 0; q < 4; ++q) {
                float phi = pp[l*12 + q*3 + 0];
                float tht = pp[l*12 + q*3 + 1];
                float omg = pp[l*12 + q*3 + 2];
                float st, ct; sincosf(0.5f*tht, &st, &ct);
                float sA, cA, sB, cB;
                sincosf(0.5f*(phi + omg), &sA, &cA);
                sincosf(0.5f*(phi - omg), &sB, &cB);
                float u00r =  cA*ct, u00i = -sA*ct;
                float u01r = -cB*st, u01i = -sB*st;
                Ur[idx][q] = rfl(u00r);
                Wi[idx][q] = rfl(u01i);
                vA[idx][q] = ZQ[q] * u00i;
                vB[idx][q] = ZQ[q] * u01r;
            }
        }
    }

    // ---- KAN: lane mu_k computes h_k (Walsh-mask placement); others zero.
    // mu: h0->lane4, h1->lane8, h2->lane1, h3->lane2, h4->lane12, h5->lane9, h6->lane3.
    int kk = -1;
    if      (lane16 == 4)  kk = 0;
    else if (lane16 == 8)  kk = 1;
    else if (lane16 == 1)  kk = 2;
    else if (lane16 == 2)  kk = 3;
    else if (lane16 == 12) kk = 4;
    else if (lane16 == 9)  kk = 5;
    else if (lane16 == 3)  kk = 6;
    float Q1c[4], Q2c[4], Q3c[4], BWc[4], QS = 0.f;
#pragma unroll
    for (int j = 0; j < 4; ++j) {
        float q0c = 0.f, q1c = 0.f, q2c = 0.f, q3c = 0.f, bwc = 0.f;
        if (kk >= 0) {
            float sw0 = ksw[kk*16 + j*4 + 0], sw1 = ksw[kk*16 + j*4 + 1];
            float sw2 = ksw[kk*16 + j*4 + 2], sw3 = ksw[kk*16 + j*4 + 3];
            const float f = REVC / 48.0f;
            q0c = f * (sw0 + 23.f*sw1 + 23.f*sw2 + sw3);
            q1c = f * (-3.f*sw0 - 15.f*sw1 + 15.f*sw2 + 3.f*sw3);
            q2c = f * (3.f*sw0 - 3.f*sw1 - 3.f*sw2 + 3.f*sw3);
            q3c = f * (-sw0 + 3.f*sw1 - 3.f*sw2 + sw3);
            bwc = REVC * kbw[kk*4 + j];
        }
        Q1c[j] = q1c; Q2c[j] = q2c; Q3c[j] = q3c; BWc[j] = bwc; QS += q0c;
    }

    // ---- initial SIG (per-lane feature-map phase, revolutions)
    float SIG;
    {
        const float* it = initial_t + (long)e*7;
        float h0 = REVC*it[0], h1 = REVC*it[1], h2 = REVC*it[2], h3 = REVC*it[3];
        float h4 = REVC*it[4], h5 = REVC*it[5], h6 = REVC*it[6];
        SIG = Z0*h0;
        SIG = fmaf(Z1, h1, SIG);
        SIG = fmaf(Z2, h2, SIG);
        SIG = fmaf(Z3, h3, SIG);
        SIG = fmaf(M01, h4, SIG);
        SIG = fmaf(M12, h5, SIG);
        SIG = fmaf(M23, h6, SIG);
    }

    const float4* inp4 = (const float4*)inputs;
    const long basei = (long)e * S;
    float4 xc = inp4[basei];
    float xk = 0.f;

#pragma unroll 1
    for (int t = 0; t < S; ++t) {
        const int tn = (t + 1 < S) ? t + 1 : S - 1;
        float4 xn = inp4[basei + tn];

        // ---- fm(hidden) on |0000>: amp = e^{i*2pi*SIG}
        float ar, ai;
        fsincos(SIG, &ai, &ar);

        // ---- ansatz(p1), fm(x), ansatz(p2).
        // Layer-2 CNOT(3,0) folded into fm_x (SGM); layer-4 ring folded into
        // the measurement Walsh masks.
#pragma unroll
        for (int l = 0; l < 4; ++l) {
            // Rot q0 (bit2), q1 (bit3), q2 (bit0), q3 (bit1)
            { float pr = lx4f(ar), pi = lx4f(ai);
              rotd(ar, ai, pr, pi, Ur[l][0], Wi[l][0], vA[l][0], vB[l][0]); }
            { float pr = lx8f(ar), pi = lx8f(ai);
              rotd(ar, ai, pr, pi, Ur[l][1], Wi[l][1], vA[l][1], vB[l][1]); }
            { float pr = lx1f(ar), pi = lx1f(ai);
              rotd(ar, ai, pr, pi, Ur[l][2], Wi[l][2], vA[l][2], vB[l][2]); }
            { float pr = lx2f(ar), pi = lx2f(ai);
              rotd(ar, ai, pr, pi, Ur[l][3], Wi[l][3], vA[l][3], vB[l][3]); }
            if (l < 3) {
                // CNOT(0,1): control qubit0(bit2), target qubit1(bit3)
                { float vr = lx8f(ar), vi = lx8f(ai);
                  ar = B2 ? vr : ar; ai = B2 ? vi : ai; }
                // merged CNOT(1,2)+CNOT(2,3): select on control qubit1(bit3)
                { float c6r = qperm<0x6C>(ar), c3r = qperm<0x39>(ar);
                  float c6i = qperm<0x6C>(ai), c3i = qperm<0x39>(ai);
                  ar = B3 ? c3r : c6r; ai = B3 ? c3i : c6i; }
                if (l != 1) {
                    // CNOT(3,0): control qubit3(bit1), target qubit0(bit2)
                    float vr = lx4f(ar), vi = lx4f(ai);
                    ar = B1 ? vr : ar; ai = B1 ? vi : ai;
                }
            }
            if (l == 1) {
                // ---- fm(x_embed): H^{x4} (unscaled) + diag phase
                float hx0 = REVC*xc.x, hx1 = REVC*xc.y, hx2 = REVC*xc.z, hx3 = REVC*xc.w;
                float u0 = fmaf(4.f, hx0, 1.f);
                float u1 = fmaf(4.f, hx1, 1.f);
                float u2 = fmaf(4.f, hx2, 1.f);
                float u3 = fmaf(4.f, hx3, 1.f);
                float he4 = NQPI * (u0*u1);
                float he5 = NQPI * (u1*u2);
                float he6 = NQPI * (u2*u3);
                // H q0 (bit2) + folded CNOT(3,0) sign SGM
                { float pr = lx4f(ar), pi = lx4f(ai);
                  ar = fmaf(Z0, ar, pr) * SGM;
                  ai = fmaf(Z0, ai, pi) * SGM; }
                // H q1 (bit3)
                { float pr = lx8f(ar), pi = lx8f(ai);
                  ar = fmaf(Z1, ar, pr); ai = fmaf(Z1, ai, pi); }
                // H q2 (bit0)
                { float pr = lx1f(ar), pi = lx1f(ai);
                  ar = fmaf(Z2, ar, pr); ai = fmaf(Z2, ai, pi); }
                // H q3 (bit1)
                { float pr = lx2f(ar), pi = lx2f(ai);
                  ar = fmaf(Z3, ar, pr); ai = fmaf(Z3, ai, pi); }
                // diag phase
                float sigx = Z0*hx0;
                sigx = fmaf(Z1, hx1, sigx);
                sigx = fmaf(Z2, hx2, sigx);
                sigx = fmaf(Z3, hx3, sigx);
                sigx = fmaf(M01, he4, sigx);
                sigx = fmaf(M12, he5, sigx);
                sigx = fmaf(M23, he6, sigx);
                float s, c;
                fsincos(sigx, &s, &c);
                float nr = ar*c - ai*s;
                float ni = ai*c + ar*s;
                ar = nr; ai = ni;
            }
        }

        // ---- measurement: layer-4 ring folded -> Walsh masks (lane bits):
        // ev0:{b0,b1,b3} ev1:{b2,b3} ev2:{b0,b2,b3} ev3:{b0,b1,b2,b3}
        {
            float p = fmaf(ai, ai, ar*ar);      // prob x256
            float w = E3 * p;                   // bit3 presign
            float r = w + lx8f(w);              // bit3-signed reduce, UNIFORM T3
            float m1 = lx1f(r);
            float rA = r - m1;                  // chain A bit0 (twist -1)
            float rB = r + m1;                  // chain B bit0 (twist +1)
            rA = fmaf(TA1, lx2f(rA), rA);       // chain A bit1
            rB = rB + lx2f(rB);                 // chain B bit1 (+1)
            rA = fmaf(TA2, lx4f(rA), rA);       // chain A bit2
            rB = rB - lx4f(rB);                 // chain B bit2 (-1, dest Z0)
            float pre = isC1 ? rB : rA;         // class j holds ev_j (pre-sign)
            xk = pre * SCL;
        }

        // ---- KAN: silu per dim-lane, quad broadcast, h at mu-lanes, WHT->SIG
        {
            float xq0 = qperm<0x00>(xk), xq1 = qperm<0x55>(xk);
            float xq2 = qperm<0xAA>(xk), xq3 = qperm<0xFF>(xk);
            float eneg = __builtin_amdgcn_exp2f(xk * -1.44269504088896f);
            float sl = xk * __builtin_amdgcn_rcpf(1.0f + eneg);
            float sq0 = qperm<0x00>(sl), sq1 = qperm<0x55>(sl);
            float sq2 = qperm<0xAA>(sl), sq3 = qperm<0xFF>(sl);
            float h = QS;
            { float tpoly = fmaf(Q3c[0], xq0, Q2c[0]);
              tpoly = fmaf(tpoly, xq0, Q1c[0]);
              h = fmaf(tpoly, xq0, h);
              h = fmaf(BWc[0], sq0, h); }
            { float tpoly = fmaf(Q3c[1], xq1, Q2c[1]);
              tpoly = fmaf(tpoly, xq1, Q1c[1]);
              h = fmaf(tpoly, xq1, h);
              h = fmaf(BWc[1], sq1, h); }
            { float tpoly = fmaf(Q3c[2], xq2, Q2c[2]);
              tpoly = fmaf(tpoly, xq2, Q1c[2]);
              h = fmaf(tpoly, xq2, h);
              h = fmaf(BWc[2], sq2, h); }
            { float tpoly = fmaf(Q3c[3], xq3, Q2c[3]);
              tpoly = fmaf(tpoly, xq3, Q1c[3]);
              h = fmaf(tpoly, xq3, h);
              h = fmaf(BWc[3], sq3, h); }
            // 4-round WHT (own-twist form): SIG(d) = sum_k h_k (-1)^{<d,mu_k>}
            h = fmaf(Z2, h, lx1f(h));   // bit0
            h = fmaf(Z3, h, lx2f(h));   // bit1
            h = fmaf(Z0, h, lx4f(h));   // bit2
            SIG = fmaf(Z1, h, lx8f(h)); // bit3
        }

        xc = xn;
    }

    // ---- classifier head: broadcast ev0..3, lane 0 writes
    {
        float xq0 = qperm<0x00>(xk), xq1 = qperm<0x55>(xk);
        float xq2 = qperm<0xAA>(xk), xq3 = qperm<0xFF>(xk);
        if (lane16 == 0) {
            float acc = cb2[0];
#pragma unroll
            for (int i = 0; i < 16; ++i) {
                float h = cb1[i] + w1[i*4+0]*xq0 + w1[i*4+1]*xq1
                        + w1[i*4+2]*xq2 + w1[i*4+3]*xq3;
                h = fmaxf(h, 0.0f);
                acc += w2[i]*h;
            }
            out[e] = acc;
        }
    }
}

extern "C" void kernel_launch(void* const* d_in, const int* in_sizes, int n_in,
                              void* d_out, int out_size, void* d_ws, size_t ws_size,
                              hipStream_t stream) {
    const float* inputs    = (const float*)d_in[0];
    const float* initial_t = (const float*)d_in[1];
    const float* p1        = (const float*)d_in[2];
    const float* p2        = (const float*)d_in[3];
    const float* kbw       = (const float*)d_in[4];
    const float* ksw       = (const float*)d_in[5];
    const float* w1        = (const float*)d_in[6];
    const float* cb1       = (const float*)d_in[7];
    const float* w2        = (const float*)d_in[8];
    const float* cb2       = (const float*)d_in[9];

    const int B = in_sizes[1] / 7;            // 16384
    const int S = in_sizes[0] / (B * 4);      // 256

    const int threads = B * 16;               // 16 lanes per element
    const int block = 256;
    const int grid = (threads + block - 1) / block;   // 1024 blocks -> 4 waves/SIMD

    qrnn_kernel<<<grid, block, 0, stream>>>(inputs, initial_t, p1, p2, kbw, ksw,
                                            w1, cb1, w2, cb2, (float*)d_out, B, S);
}